// Round 4
// baseline (173.069 us; speedup 1.0000x reference)
//
#include <hip/hip_runtime.h>
#include <math.h>

#define J   29
#define CH  3
#define JC  87            // J*CH
#define E0  56
#define B   256
#define T   1024
#define FRAMES (B*T)      // 262144
#define FPC 64            // frames per chunk (= wave size)
#define CPB 2             // chunks per block
#define NBLK (FRAMES/(FPC*CPB)) // 2048
#define CHUNK_FLOATS (FPC*JC)   // 5568 floats
#define CHUNK_BYTES (CHUNK_FLOATS*4) // 22272
#define BPB (T/(FPC*CPB)) // 8 partials per batch
#define SLOTS 6           // padded nnz per row (overflow list beyond)
#define MAXOV 96          // overflow capacity (nnz total <= 85)

typedef const __attribute__((address_space(1))) void* gas_p;
typedef __attribute__((address_space(3))) void* las_p;

// ---------------- prep: M = D^-1/2(A+I)D^-1/2 as padded-6 slots + overflow --
__global__ void prep_kernel(const int* __restrict__ ei,
                            int2* __restrict__ pairs,    // [J*SLOTS] {col*12, val}
                            int*  __restrict__ ov_rp,    // [J+1]
                            int2* __restrict__ ov_pairs) // [MAXOV]
{
    __shared__ float M[J * J];
    __shared__ float dinv[J];
    __shared__ int   cnt_ov[J];
    int tid = threadIdx.x;

    for (int i = tid; i < J * J; i += 64) M[i] = 0.f;
    if (tid < J) {
        int d = 1;
        for (int e = 0; e < E0; ++e) d += (ei[E0 + e] == tid) ? 1 : 0;
        dinv[tid] = rsqrtf((float)d);
    }
    __syncthreads();

    if (tid < J) {
        for (int e = 0; e < E0; ++e) {
            if (ei[E0 + e] == tid) {
                int s = ei[e];
                M[tid * J + s] += dinv[s] * dinv[tid];
            }
        }
        M[tid * J + tid] += dinv[tid] * dinv[tid];
        int c = 0;
        for (int i = 0; i < J; ++i) c += (M[tid * J + i] != 0.f) ? 1 : 0;
        cnt_ov[tid] = (c > SLOTS) ? (c - SLOTS) : 0;
    }
    __syncthreads();

    if (tid == 0) {
        int a = 0;
        for (int j = 0; j < J; ++j) { ov_rp[j] = a; a += cnt_ov[j]; }
        ov_rp[J] = a;
    }
    __syncthreads();

    if (tid < J) {
        int s = 0, p = ov_rp[tid];
        for (int i = 0; i < J; ++i) {
            float v = M[tid * J + i];
            if (v != 0.f) {
                int2 pr; pr.x = i * 12; pr.y = __float_as_int(v);
                if (s < SLOTS) pairs[tid * SLOTS + s] = pr;
                else           ov_pairs[p++] = pr;
                ++s;
            }
        }
        for (; s < SLOTS; ++s) { int2 pr; pr.x = 0; pr.y = 0; pairs[tid * SLOTS + s] = pr; }
    }
    // zero-fill unused overflow capacity so main can blind-load MAXOV entries
    __syncthreads();
    if (tid == 0) {
        int a = ov_rp[J];
        for (int i = a; i < MAXOV; ++i) { int2 pr; pr.x = 0; pr.y = 0; ov_pairs[i] = pr; }
    }
}

// stage one 64-frame chunk (22272 B): 21 x 1024B rounds of 16B/lane + one
// overlapping tail round at byte 21248 (rewrites 256B identically — benign).
__device__ __forceinline__ void stage_chunk(const char* __restrict__ s,
                                            char* d, int lane) {
#pragma unroll
    for (int i = 0; i < 21; ++i) {
        __builtin_amdgcn_global_load_lds((gas_p)(s + i * 1024 + lane * 16),
                                         (las_p)(d + i * 1024), 16, 0, 0);
    }
    __builtin_amdgcn_global_load_lds((gas_p)(s + 21248 + lane * 16),
                                     (las_p)(d + 21248), 16, 0, 0);
}

// ---------------- main: 1 wave/block, 2 chunks, double-buffered staging -----
__launch_bounds__(64, 1)
__global__ void gcn_main(const float* __restrict__ x,
                         const float* __restrict__ Wp,
                         const float* __restrict__ bp,
                         const int2* __restrict__ pairs,
                         const int*  __restrict__ ov_rp,
                         const int2* __restrict__ ov_pairs,
                         float* __restrict__ partials) {
    __shared__ float xs[2][CHUNK_FLOATS];   // 2 x 22272 B
    __shared__ int2  s_pairs[J * SLOTS];    // static-address b64 broadcast reads
    __shared__ int2  s_ovp[MAXOV];
    __shared__ int   s_ovrp[J + 1];
    __shared__ float s_W[9];
    __shared__ float s_b[3];

    int lane = threadIdx.x;

    if (lane < 9)  s_W[lane] = Wp[lane];
    if (lane < 3)  s_b[lane] = bp[lane];
    if (lane <= J) s_ovrp[lane] = ov_rp[lane];
    for (int i = lane; i < J * SLOTS; i += 64) s_pairs[i] = pairs[i];
    for (int i = lane; i < MAXOV; i += 64)     s_ovp[i]  = ov_pairs[i];
    __syncthreads();   // drain small loads; no chunk staging in flight yet

    const char* src = (const char*)(x + (size_t)blockIdx.x * (CPB * CHUNK_FLOATS));
    stage_chunk(src, (char*)xs[0], lane);

    float acc[J][CH];
#pragma unroll
    for (int j = 0; j < J; ++j)
#pragma unroll
        for (int c = 0; c < CH; ++c) acc[j][c] = 0.f;

#pragma unroll
    for (int c = 0; c < CPB; ++c) {
        // wait for chunk c (only outstanding vmem), then fire chunk c+1 so it
        // stays in flight across the compute below
        asm volatile("s_waitcnt vmcnt(0)" ::: "memory");
        __builtin_amdgcn_sched_barrier(0);
        if (c + 1 < CPB)
            stage_chunk(src + (size_t)(c + 1) * CHUNK_BYTES, (char*)xs[(c + 1) & 1], lane);

        const char* xf = (const char*)xs[c & 1] + lane * (JC * 4);
#pragma unroll
        for (int j = 0; j < J; ++j) {
            float a0 = 0.f, a1 = 0.f, a2 = 0.f;
#pragma unroll
            for (int s = 0; s < SLOTS; ++s) {
                int2 pr = s_pairs[j * SLOTS + s];     // ds_read_b64, static addr
                float v = __int_as_float(pr.y);
                const float* q = (const float*)(xf + pr.x);
                a0 += v * q[0];
                a1 += v * q[1];
                a2 += v * q[2];
            }
            // overflow entries (deg > SLOTS) — wave-uniform, usually empty
            int e0 = s_ovrp[j], e1 = s_ovrp[j + 1];
            for (int e = e0; e < e1; ++e) {
                int2 pr = s_ovp[e];
                float v = __int_as_float(pr.y);
                const float* q = (const float*)(xf + pr.x);
                a0 += v * q[0];
                a1 += v * q[1];
                a2 += v * q[2];
            }
#pragma unroll
            for (int ch = 0; ch < CH; ++ch) {
                float t = a0 * s_W[0 * CH + ch]
                        + a1 * s_W[1 * CH + ch]
                        + a2 * s_W[2 * CH + ch]
                        + s_b[ch];
                acc[j][ch] += fmaxf(t, 0.f);
            }
        }
    }

    // block-level reduce of 64 per-thread 87-vectors (xs[0] is free: last
    // chunk computed from xs[1])
    float* red = xs[0];
#pragma unroll
    for (int j = 0; j < J; ++j)
#pragma unroll
        for (int ch = 0; ch < CH; ++ch)
            red[lane * JC + j * CH + ch] = acc[j][ch];
    __syncthreads();

#pragma unroll
    for (int s = 32; s >= 1; s >>= 1) {
        for (int w = lane; w < s * JC; w += 64) {
            int t = w % s, r = w / s;
            red[t * JC + r] += red[(t + s) * JC + r];
        }
        __syncthreads();
    }

    for (int w = lane; w < JC; w += 64)
        partials[(size_t)blockIdx.x * JC + w] = red[w];
}

// ---------------- finalize: mean over frames + fc + sigmoid ------------------
__global__ void finalize_kernel(const float* __restrict__ partials,
                                const float* __restrict__ fcW,
                                const float* __restrict__ fcb,
                                float* __restrict__ out) {
    __shared__ float h[JC];
    int b = blockIdx.x, tid = threadIdx.x;
    if (tid < JC) {
        float a = 0.f;
#pragma unroll
        for (int p = 0; p < BPB; ++p)
            a += partials[(size_t)(b * BPB + p) * JC + tid];
        a *= (1.0f / (float)T);
        h[tid] = a;
        out[(size_t)b * JC + tid] = a;
    }
    __syncthreads();
    if (tid < 2) {
        float a = fcb[tid];
        for (int r = 0; r < JC; ++r) a += h[r] * fcW[r * 2 + tid];
        out[(size_t)B * JC + b * 2 + tid] = 1.0f / (1.0f + expf(-a));
    }
}

extern "C" void kernel_launch(void* const* d_in, const int* in_sizes, int n_in,
                              void* d_out, int out_size, void* d_ws, size_t ws_size,
                              hipStream_t stream) {
    const float* x   = (const float*)d_in[0];
    const int*   ei  = (const int*)d_in[1];
    const float* W   = (const float*)d_in[4];
    const float* bb  = (const float*)d_in[5];
    const float* fcW = (const float*)d_in[6];
    const float* fcb = (const float*)d_in[7];

    char* ws = (char*)d_ws;
    int2* pairs    = (int2*)ws;                       // 174 * 8B
    int2* ov_pairs = pairs + J * SLOTS;               // 96 * 8B
    int*  ov_rp    = (int*)(ov_pairs + MAXOV);        // 32 * 4B
    float* partials = (float*)(ws + 4096);            // 2048*87 floats

    prep_kernel<<<1, 64, 0, stream>>>(ei, pairs, ov_rp, ov_pairs);
    gcn_main<<<NBLK, 64, 0, stream>>>(x, W, bb, pairs, ov_rp, ov_pairs, partials);
    finalize_kernel<<<B, 128, 0, stream>>>(partials, fcW, fcb, (float*)d_out);
}

// Round 5
// 128.775 us; speedup vs baseline: 1.3440x; 1.3440x over previous
//
#include <hip/hip_runtime.h>
#include <math.h>

#define J   29
#define CH  3
#define JC  87            // J*CH
#define E0  56
#define B   256
#define T   1024
#define FRAMES (B*T)      // 262144
#define FPC 64            // frames per chunk (= wave size)
#define CPB 2             // chunks per block
#define NBLK (FRAMES/(FPC*CPB)) // 2048
#define CHUNK_FLOATS (FPC*JC)   // 5568 floats
#define CHUNK_BYTES (CHUNK_FLOATS*4) // 22272
#define BPB (T/(FPC*CPB)) // 8 partials per batch
#define SLOTS 6           // padded nnz per row
#define PROWS 30          // padded row count (row 29 = zeros)
#define MAXOV 96          // overflow capacity

typedef const __attribute__((address_space(1))) void* gas_p;
typedef __attribute__((address_space(3))) void* las_p;

// ---------------- prep: M = D^-1/2(A+I)D^-1/2, padded-6 slots + overflow ----
__global__ void prep_kernel(const int* __restrict__ ei,
                            int2* __restrict__ pairs,    // [PROWS*SLOTS]
                            int*  __restrict__ ov_rp,    // [J+1]
                            int2* __restrict__ ov_pairs) // [MAXOV]
{
    __shared__ float M[J * J];
    __shared__ float dinv[J];
    __shared__ int   cnt_ov[J];
    int tid = threadIdx.x;

    for (int i = tid; i < J * J; i += 64) M[i] = 0.f;
    if (tid < J) {
        int d = 1;
        for (int e = 0; e < E0; ++e) d += (ei[E0 + e] == tid) ? 1 : 0;
        dinv[tid] = rsqrtf((float)d);
    }
    __syncthreads();

    if (tid < J) {
        for (int e = 0; e < E0; ++e) {
            if (ei[E0 + e] == tid) {
                int s = ei[e];
                M[tid * J + s] += dinv[s] * dinv[tid];
            }
        }
        M[tid * J + tid] += dinv[tid] * dinv[tid];
        int c = 0;
        for (int i = 0; i < J; ++i) c += (M[tid * J + i] != 0.f) ? 1 : 0;
        cnt_ov[tid] = (c > SLOTS) ? (c - SLOTS) : 0;
    }
    __syncthreads();

    if (tid == 0) {
        int a = 0;
        for (int j = 0; j < J; ++j) { ov_rp[j] = a; a += cnt_ov[j]; }
        ov_rp[J] = a;
    }
    __syncthreads();

    if (tid < PROWS) {
        int2 zero; zero.x = 0; zero.y = 0;
        if (tid < J) {
            int s = 0, p = ov_rp[tid];
            for (int i = 0; i < J; ++i) {
                float v = M[tid * J + i];
                if (v != 0.f) {
                    int2 pr; pr.x = i * 12; pr.y = __float_as_int(v);
                    if (s < SLOTS) pairs[tid * SLOTS + s] = pr;
                    else           ov_pairs[p++] = pr;
                    ++s;
                }
            }
            for (; s < SLOTS; ++s) pairs[tid * SLOTS + s] = zero;
        } else {
            for (int s = 0; s < SLOTS; ++s) pairs[tid * SLOTS + s] = zero;
        }
    }
    __syncthreads();
    if (tid == 0) {
        int a = ov_rp[J];
        for (int i = a; i < MAXOV; ++i) { int2 pr; pr.x = 0; pr.y = 0; ov_pairs[i] = pr; }
    }
}

// ---------------- main: 2 waves/block, joints split 15/14, 6 blocks/CU ------
__launch_bounds__(128, 3)
__global__ void gcn_main(const float* __restrict__ x,
                         const float* __restrict__ Wp,
                         const float* __restrict__ bp,
                         const int2* __restrict__ pairs,
                         const int*  __restrict__ ov_rp,
                         const int2* __restrict__ ov_pairs,
                         float* __restrict__ partials) {
    __shared__ float xs[CHUNK_FLOATS];       // 22272 B, single buffer; reused for reduce
    __shared__ int2  s_pairs[PROWS * SLOTS]; // 180 entries
    __shared__ int2  s_ovp[MAXOV];
    __shared__ int   s_ovrp[32];
    __shared__ float s_W[9];
    __shared__ float s_b[3];

    int tid  = threadIdx.x;
    int lane = tid & 63;
    int wv   = tid >> 6;

    if (tid < 9)  s_W[tid] = Wp[tid];
    if (tid >= 16 && tid < 19) s_b[tid - 16] = bp[tid - 16];
    if (tid >= 32 && tid < 63) s_ovrp[tid - 32] = ov_rp[(tid - 32 < J) ? (tid - 32) : J];
    for (int i = tid; i < PROWS * SLOTS; i += 128) s_pairs[i] = pairs[i];
    for (int i = tid; i < MAXOV; i += 128)         s_ovp[i]  = ov_pairs[i];

    const char* src = (const char*)(x + (size_t)blockIdx.x * (CPB * CHUNK_FLOATS));
    char* dst = (char*)xs;

    int jbase = wv * 15;                   // wave0: rows 0..14, wave1: 15..29 (29=pad)
    const char* xf = (const char*)xs + lane * (JC * 4);

    float acc[15][CH];
#pragma unroll
    for (int r = 0; r < 15; ++r)
#pragma unroll
        for (int c = 0; c < CH; ++c) acc[r][c] = 0.f;

    for (int c = 0; c < CPB; ++c) {
        __syncthreads();   // previous chunk's reads done (and structure writes visible)
        // stage chunk c: 22 x 1KB rounds of 16B/lane, split across the 2 waves
        const char* s = src + (size_t)c * CHUNK_BYTES;
        if (wv == 0) {
#pragma unroll
            for (int r = 0; r < 11; ++r)
                __builtin_amdgcn_global_load_lds((gas_p)(s + r * 1024 + lane * 16),
                                                 (las_p)(dst + r * 1024), 16, 0, 0);
        } else {
#pragma unroll
            for (int r = 11; r < 21; ++r)
                __builtin_amdgcn_global_load_lds((gas_p)(s + r * 1024 + lane * 16),
                                                 (las_p)(dst + r * 1024), 16, 0, 0);
            // tail: rewrites 256B identically — benign
            __builtin_amdgcn_global_load_lds((gas_p)(s + 21248 + lane * 16),
                                             (las_p)(dst + 21248), 16, 0, 0);
        }
        asm volatile("s_waitcnt vmcnt(0)" ::: "memory");
        __syncthreads();

#pragma unroll
        for (int JR = 0; JR < 15; ++JR) {
            if ((JR % 5) == 0) __builtin_amdgcn_sched_barrier(0);  // cap hoist window
            int j = jbase + JR;            // wave-uniform
            const int2* rowp = s_pairs + j * SLOTS;
            float a0 = 0.f, a1 = 0.f, a2 = 0.f;
#pragma unroll
            for (int sl = 0; sl < SLOTS; ++sl) {
                int2 pr = rowp[sl];        // ds_read_b64 broadcast
                float v = __int_as_float(pr.y);
                const float* q = (const float*)(xf + pr.x);
                a0 += v * q[0];
                a1 += v * q[1];
                a2 += v * q[2];
            }
            int e0 = s_ovrp[j], e1 = s_ovrp[j + 1]; // row 29: both = total -> empty
            for (int e = e0; e < e1; ++e) {
                int2 pr = s_ovp[e];
                float v = __int_as_float(pr.y);
                const float* q = (const float*)(xf + pr.x);
                a0 += v * q[0];
                a1 += v * q[1];
                a2 += v * q[2];
            }
#pragma unroll
            for (int ch = 0; ch < CH; ++ch) {
                float t = a0 * s_W[0 * CH + ch]
                        + a1 * s_W[1 * CH + ch]
                        + a2 * s_W[2 * CH + ch]
                        + s_b[ch];
                acc[JR][ch] += fmaxf(t, 0.f);
            }
        }
    }

    __syncthreads();   // all reads of xs done; safe to overwrite as reduce buffer
    float* red = xs;
    if (jbase + 14 < J || wv == 0) {
        // wave0 writes 15 rows
#pragma unroll
        for (int JR = 0; JR < 15; ++JR)
#pragma unroll
            for (int ch = 0; ch < CH; ++ch)
                red[lane * JC + (jbase + JR) * CH + ch] = acc[JR][ch];
    } else {
        // wave1 writes 14 real rows (row 29 is padding)
#pragma unroll
        for (int JR = 0; JR < 14; ++JR)
#pragma unroll
            for (int ch = 0; ch < CH; ++ch)
                red[lane * JC + (jbase + JR) * CH + ch] = acc[JR][ch];
    }
    __syncthreads();

#pragma unroll
    for (int s = 32; s >= 1; s >>= 1) {
        for (int w = tid; w < s * JC; w += 128) {
            int t = w % s, r = w / s;
            red[t * JC + r] += red[(t + s) * JC + r];
        }
        __syncthreads();
    }

    for (int w = tid; w < JC; w += 128)
        partials[(size_t)blockIdx.x * JC + w] = red[w];
}

// ---------------- finalize: mean over frames + fc + sigmoid ------------------
__global__ void finalize_kernel(const float* __restrict__ partials,
                                const float* __restrict__ fcW,
                                const float* __restrict__ fcb,
                                float* __restrict__ out) {
    __shared__ float h[JC];
    int b = blockIdx.x, tid = threadIdx.x;
    if (tid < JC) {
        float a = 0.f;
#pragma unroll
        for (int p = 0; p < BPB; ++p)
            a += partials[(size_t)(b * BPB + p) * JC + tid];
        a *= (1.0f / (float)T);
        h[tid] = a;
        out[(size_t)b * JC + tid] = a;
    }
    __syncthreads();
    if (tid < 2) {
        float a = fcb[tid];
        for (int r = 0; r < JC; ++r) a += h[r] * fcW[r * 2 + tid];
        out[(size_t)B * JC + b * 2 + tid] = 1.0f / (1.0f + expf(-a));
    }
}

extern "C" void kernel_launch(void* const* d_in, const int* in_sizes, int n_in,
                              void* d_out, int out_size, void* d_ws, size_t ws_size,
                              hipStream_t stream) {
    const float* x   = (const float*)d_in[0];
    const int*   ei  = (const int*)d_in[1];
    const float* W   = (const float*)d_in[4];
    const float* bb  = (const float*)d_in[5];
    const float* fcW = (const float*)d_in[6];
    const float* fcb = (const float*)d_in[7];

    char* ws = (char*)d_ws;
    int2* pairs    = (int2*)ws;                       // 180 * 8B
    int2* ov_pairs = pairs + PROWS * SLOTS;           // 96 * 8B
    int*  ov_rp    = (int*)(ov_pairs + MAXOV);        // 30 * 4B
    float* partials = (float*)(ws + 4096);            // 2048*87 floats

    prep_kernel<<<1, 64, 0, stream>>>(ei, pairs, ov_rp, ov_pairs);
    gcn_main<<<NBLK, 128, 0, stream>>>(x, W, bb, pairs, ov_rp, ov_pairs, partials);
    finalize_kernel<<<B, 128, 0, stream>>>(partials, fcW, fcb, (float*)d_out);
}

// Round 6
// 75.906 us; speedup vs baseline: 2.2800x; 1.6965x over previous
//
#include <hip/hip_runtime.h>
#include <math.h>

#define J   29
#define CH  3
#define JC  87            // J*CH
#define E0  56
#define B   256
#define T   1024
#define FRAMES (B*T)      // 262144
#define FPC 64            // frames per chunk (= lanes)
#define CPB 4             // chunks per block
#define NBLK (FRAMES/(FPC*CPB)) // 1024
#define CHUNK_FLOATS (FPC*JC)   // 5568 floats
#define CHUNK_BYTES (CHUNK_FLOATS*4) // 22272
#define BPB (T/(FPC*CPB)) // 4 partials per batch
#define SLOTS 6           // padded nnz per row
#define PROWS 32          // padded row count (rows 29..31 = zeros)
#define MAXOV 96          // overflow capacity

typedef const __attribute__((address_space(1))) void* gas_p;
typedef __attribute__((address_space(3))) void* las_p;

// ---------------- prep: M = D^-1/2(A+I)D^-1/2, padded-6 slots + overflow ----
__global__ void prep_kernel(const int* __restrict__ ei,
                            int2* __restrict__ pairs,    // [PROWS*SLOTS] {col*12, val}
                            int*  __restrict__ ov_rp,    // [J+1]
                            int2* __restrict__ ov_pairs) // [MAXOV]
{
    __shared__ float M[J * J];
    __shared__ float dinv[J];
    __shared__ int   cnt_ov[J];
    int tid = threadIdx.x;

    for (int i = tid; i < J * J; i += 64) M[i] = 0.f;
    if (tid < J) {
        int d = 1;
        for (int e = 0; e < E0; ++e) d += (ei[E0 + e] == tid) ? 1 : 0;
        dinv[tid] = rsqrtf((float)d);
    }
    __syncthreads();

    if (tid < J) {
        for (int e = 0; e < E0; ++e) {
            if (ei[E0 + e] == tid) {
                int s = ei[e];
                M[tid * J + s] += dinv[s] * dinv[tid];
            }
        }
        M[tid * J + tid] += dinv[tid] * dinv[tid];
        int c = 0;
        for (int i = 0; i < J; ++i) c += (M[tid * J + i] != 0.f) ? 1 : 0;
        cnt_ov[tid] = (c > SLOTS) ? (c - SLOTS) : 0;
    }
    __syncthreads();

    if (tid == 0) {
        int a = 0;
        for (int j = 0; j < J; ++j) { ov_rp[j] = a; a += cnt_ov[j]; }
        ov_rp[J] = a;
    }
    __syncthreads();

    if (tid < PROWS) {
        int2 zero; zero.x = 0; zero.y = 0;
        if (tid < J) {
            int s = 0, p = ov_rp[tid];
            for (int i = 0; i < J; ++i) {
                float v = M[tid * J + i];
                if (v != 0.f) {
                    int2 pr; pr.x = i * 12; pr.y = __float_as_int(v);
                    if (s < SLOTS) pairs[tid * SLOTS + s] = pr;
                    else           ov_pairs[p++] = pr;
                    ++s;
                }
            }
            for (; s < SLOTS; ++s) pairs[tid * SLOTS + s] = zero;
        } else {
            for (int s = 0; s < SLOTS; ++s) pairs[tid * SLOTS + s] = zero;
        }
    }
    __syncthreads();
    if (tid == 0) {
        int a = ov_rp[J];
        for (int i = a; i < MAXOV; ++i) { int2 pr; pr.x = 0; pr.y = 0; ov_pairs[i] = pr; }
    }
}

// ---------------- main: 4 waves/block, 8 rows/wave, lane = frame ------------
__launch_bounds__(256, 4)
__global__ void gcn_main(const float* __restrict__ x,
                         const float* __restrict__ Wp,
                         const float* __restrict__ bp,
                         const int2* __restrict__ pairs,
                         const int*  __restrict__ ov_rp,
                         const int2* __restrict__ ov_pairs,
                         float* __restrict__ partials) {
    __shared__ float xs[CHUNK_FLOATS];        // 22272 B shared by all 4 waves
    __shared__ int2  s_pairs[PROWS * SLOTS];  // 192 entries
    __shared__ int2  s_ovp[MAXOV];
    __shared__ int   s_ovrp[33];
    __shared__ float s_W[9];
    __shared__ float s_b[3];

    int tid  = threadIdx.x;
    int lane = tid & 63;
    int wv   = tid >> 6;

    if (tid < 9) s_W[tid] = Wp[tid];
    if (tid >= 16 && tid < 19) s_b[tid - 16] = bp[tid - 16];
    if (tid >= 32 && tid < 65) { int i = tid - 32; s_ovrp[i] = ov_rp[(i < J + 1) ? i : J]; }
    if (tid < PROWS * SLOTS) s_pairs[tid] = pairs[tid];
    if (tid >= 128 && tid < 128 + MAXOV) s_ovp[tid - 128] = ov_pairs[tid - 128];

    const char* src = (const char*)(x + (size_t)blockIdx.x * (CPB * CHUNK_FLOATS));
    char* dst = (char*)xs;
    const int rowbase = wv * 8;               // wave w owns rows w*8 .. w*8+7

    float acc[8][CH];
#pragma unroll
    for (int r = 0; r < 8; ++r)
#pragma unroll
        for (int c = 0; c < CH; ++c) acc[r][c] = 0.f;

    for (int c = 0; c < CPB; ++c) {
        __syncthreads();   // tables visible (c=0) / previous chunk fully consumed
        // stage chunk c: 22 x 1KB issues of 16B/lane, striped across the 4 waves;
        // issue 21 starts at 21248 (rewrites 256B identically — benign)
        const char* s = src + (size_t)c * CHUNK_BYTES;
        for (int r = wv; r < 22; r += 4) {
            int off = (r < 21) ? r * 1024 : 21248;
            __builtin_amdgcn_global_load_lds((gas_p)(s + off + lane * 16),
                                             (las_p)(dst + off), 16, 0, 0);
        }
        asm volatile("s_waitcnt vmcnt(0)" ::: "memory");
        __syncthreads();

        const char* xf = (const char*)xs + lane * (JC * 4);
#pragma unroll
        for (int R = 0; R < 8; ++R) {
            int j = rowbase + R;              // wave-uniform
            const int2* rowp = s_pairs + j * SLOTS;
            float a0 = 0.f, a1 = 0.f, a2 = 0.f;
#pragma unroll
            for (int sl = 0; sl < SLOTS; ++sl) {
                int2 pr = rowp[sl];           // ds_read_b64 broadcast
                float v = __int_as_float(pr.y);
                const float* q = (const float*)(xf + pr.x);
                a0 += v * q[0];
                a1 += v * q[1];
                a2 += v * q[2];
            }
            int e0 = s_ovrp[j], e1 = s_ovrp[j + 1];  // padded rows: empty
            for (int e = e0; e < e1; ++e) {
                int2 pr = s_ovp[e];
                float v = __int_as_float(pr.y);
                const float* q = (const float*)(xf + pr.x);
                a0 += v * q[0];
                a1 += v * q[1];
                a2 += v * q[2];
            }
#pragma unroll
            for (int ch = 0; ch < CH; ++ch) {
                float t = a0 * s_W[0 * CH + ch]
                        + a1 * s_W[1 * CH + ch]
                        + a2 * s_W[2 * CH + ch]
                        + s_b[ch];
                acc[R][ch] += fmaxf(t, 0.f);
            }
        }
    }

    // per-wave butterfly reduce over the 64 lanes (frames), then lane 0 stores
#pragma unroll
    for (int R = 0; R < 8; ++R)
#pragma unroll
        for (int ch = 0; ch < CH; ++ch) {
            float v = acc[R][ch];
#pragma unroll
            for (int m = 1; m < 64; m <<= 1) v += __shfl_xor(v, m, 64);
            acc[R][ch] = v;
        }
    if (lane == 0) {
#pragma unroll
        for (int R = 0; R < 8; ++R) {
            int j = rowbase + R;
            if (j < J) {
#pragma unroll
                for (int ch = 0; ch < CH; ++ch)
                    partials[(size_t)blockIdx.x * JC + j * CH + ch] = acc[R][ch];
            }
        }
    }
}

// ---------------- finalize: mean over frames + fc + sigmoid ------------------
__global__ void finalize_kernel(const float* __restrict__ partials,
                                const float* __restrict__ fcW,
                                const float* __restrict__ fcb,
                                float* __restrict__ out) {
    __shared__ float h[JC];
    int b = blockIdx.x, tid = threadIdx.x;
    if (tid < JC) {
        float a = 0.f;
#pragma unroll
        for (int p = 0; p < BPB; ++p)
            a += partials[(size_t)(b * BPB + p) * JC + tid];
        a *= (1.0f / (float)T);
        h[tid] = a;
        out[(size_t)b * JC + tid] = a;
    }
    __syncthreads();
    if (tid < 2) {
        float a = fcb[tid];
        for (int r = 0; r < JC; ++r) a += h[r] * fcW[r * 2 + tid];
        out[(size_t)B * JC + b * 2 + tid] = 1.0f / (1.0f + expf(-a));
    }
}

extern "C" void kernel_launch(void* const* d_in, const int* in_sizes, int n_in,
                              void* d_out, int out_size, void* d_ws, size_t ws_size,
                              hipStream_t stream) {
    const float* x   = (const float*)d_in[0];
    const int*   ei  = (const int*)d_in[1];
    const float* W   = (const float*)d_in[4];
    const float* bb  = (const float*)d_in[5];
    const float* fcW = (const float*)d_in[6];
    const float* fcb = (const float*)d_in[7];

    char* ws = (char*)d_ws;
    int2* pairs    = (int2*)ws;                       // 192 * 8B
    int2* ov_pairs = pairs + PROWS * SLOTS;           // 96 * 8B
    int*  ov_rp    = (int*)(ov_pairs + MAXOV);        // 30 * 4B
    float* partials = (float*)(ws + 4096);            // 1024*87 floats

    prep_kernel<<<1, 64, 0, stream>>>(ei, pairs, ov_rp, ov_pairs);
    gcn_main<<<NBLK, 256, 0, stream>>>(x, W, bb, pairs, ov_rp, ov_pairs, partials);
    finalize_kernel<<<B, 128, 0, stream>>>(partials, fcW, fcb, (float*)d_out);
}

// Round 7
// 44.350 us; speedup vs baseline: 3.9024x; 1.7115x over previous
//
#include <hip/hip_runtime.h>
#include <math.h>

#define J   29
#define CH  3
#define JC  87            // J*CH
#define E0  56
#define B   256
#define T   1024
#define FRAMES (B*T)      // 262144
#define FPC 64            // frames per chunk (= lanes)
#define CPB 4             // chunks per block
#define NBLK (FRAMES/(FPC*CPB)) // 1024
#define CHUNK_FLOATS (FPC*JC)   // 5568 floats
#define CHUNK_BYTES (CHUNK_FLOATS*4) // 22272
#define BPB (T/(FPC*CPB)) // 4 partials per batch
#define SLOTS 6           // padded nnz per row
#define PROWS 32          // padded row count (rows 29..31 = zeros)
#define MAXOV 96          // overflow capacity
#define WAVES 8           // waves per main block
#define RPW 4             // rows per wave

typedef const __attribute__((address_space(1))) void* gas_p;
typedef __attribute__((address_space(3))) void* las_p;

// ---- prep: M = D^-1/2(A+I)D^-1/2 as padded-6 slots + row-tagged overflow ---
__global__ void prep_kernel(const int* __restrict__ ei,
                            int2* __restrict__ pairs,    // [PROWS*SLOTS] {col*12, val}
                            int*  __restrict__ ov_rp,    // [33]
                            int2* __restrict__ ov_pairs) // [MAXOV] {row<<16|col*12, val}
{
    __shared__ float M[J * J];
    __shared__ float dinv[J];
    __shared__ int   cnt_ov[J];
    int tid = threadIdx.x;

    for (int i = tid; i < J * J; i += 64) M[i] = 0.f;
    if (tid < J) {
        int d = 1;
        for (int e = 0; e < E0; ++e) d += (ei[E0 + e] == tid) ? 1 : 0;
        dinv[tid] = rsqrtf((float)d);
    }
    __syncthreads();

    if (tid < J) {
        for (int e = 0; e < E0; ++e) {
            if (ei[E0 + e] == tid) {
                int s = ei[e];
                M[tid * J + s] += dinv[s] * dinv[tid];
            }
        }
        M[tid * J + tid] += dinv[tid] * dinv[tid];
        int c = 0;
        for (int i = 0; i < J; ++i) c += (M[tid * J + i] != 0.f) ? 1 : 0;
        cnt_ov[tid] = (c > SLOTS) ? (c - SLOTS) : 0;
    }
    __syncthreads();

    if (tid == 0) {
        int a = 0;
        for (int j = 0; j < J; ++j) { ov_rp[j] = a; a += cnt_ov[j]; }
        for (int j = J; j <= 32; ++j) ov_rp[j] = a;   // rows 29..31 empty
    }
    __syncthreads();

    if (tid < PROWS) {
        int2 zero; zero.x = 0; zero.y = 0;
        if (tid < J) {
            int s = 0, p = ov_rp[tid];
            for (int i = 0; i < J; ++i) {
                float v = M[tid * J + i];
                if (v != 0.f) {
                    if (s < SLOTS) {
                        int2 pr; pr.x = i * 12; pr.y = __float_as_int(v);
                        pairs[tid * SLOTS + s] = pr;
                    } else {
                        int2 pr; pr.x = (tid << 16) | (i * 12); pr.y = __float_as_int(v);
                        ov_pairs[p++] = pr;
                    }
                    ++s;
                }
            }
            for (; s < SLOTS; ++s) pairs[tid * SLOTS + s] = zero;
        } else {
            for (int s = 0; s < SLOTS; ++s) pairs[tid * SLOTS + s] = zero;
        }
    }
}

// ---- main: 8 waves/block, 4 rows/wave, lane = frame, tables in SGPRs -------
__launch_bounds__(512, 6)
__global__ void gcn_main(const float* __restrict__ x,
                         const float* __restrict__ Wp,
                         const float* __restrict__ bp,
                         const int2* __restrict__ pairs,
                         const int*  __restrict__ ov_rp,
                         const int2* __restrict__ ov_pairs,
                         float* __restrict__ partials) {
    __shared__ float xs[CHUNK_FLOATS];    // 22272 B — the ONLY LDS use

    int tid  = threadIdx.x;
    int lane = tid & 63;
    int wv   = tid >> 6;
    int rowbase = __builtin_amdgcn_readfirstlane(wv * RPW);  // uniform: 0,4,..,28

    // wave-uniform small tables -> scalar loads, hoisted out of the chunk loop
    float sW[9], sb[CH];
#pragma unroll
    for (int i = 0; i < 9; ++i) sW[i] = Wp[i];
#pragma unroll
    for (int i = 0; i < CH; ++i) sb[i] = bp[i];
    int ov0 = ov_rp[rowbase], ov1 = ov_rp[rowbase + RPW];

    const char* src = (const char*)(x + (size_t)blockIdx.x * (CPB * CHUNK_FLOATS));
    char* dst = (char*)xs;

    float acc[RPW][CH];
#pragma unroll
    for (int r = 0; r < RPW; ++r)
#pragma unroll
        for (int c = 0; c < CH; ++c) acc[r][c] = 0.f;

    for (int c = 0; c < CPB; ++c) {
        __syncthreads();   // previous chunk fully consumed
        const char* s = src + (size_t)c * CHUNK_BYTES;
        for (int r = wv; r < 22; r += WAVES) {
            int off = (r < 21) ? r * 1024 : 21248;   // tail rewrites 256B identically
            __builtin_amdgcn_global_load_lds((gas_p)(s + off + lane * 16),
                                             (las_p)(dst + off), 16, 0, 0);
        }
        asm volatile("s_waitcnt vmcnt(0)" ::: "memory");
        __syncthreads();

        const char* xf = (const char*)xs + lane * (JC * 4);

        // --- phase 1: static gather, y[R] fully register-resident -----------
        float y[RPW][CH];
#pragma unroll
        for (int R = 0; R < RPW; ++R) {
            float a0 = 0.f, a1 = 0.f, a2 = 0.f;
#pragma unroll
            for (int sl = 0; sl < SLOTS; ++sl) {
                int2 pr = pairs[(rowbase + R) * SLOTS + sl];  // SGPR (uniform)
                float v = __int_as_float(pr.y);
                const float* q = (const float*)(xf + pr.x);
                a0 += v * q[0];
                a1 += v * q[1];
                a2 += v * q[2];
            }
            y[R][0] = a0; y[R][1] = a1; y[R][2] = a2;
        }

        // --- phase 2: overflow (uniform bounds, STATIC y indices) -----------
        for (int e = ov0; e < ov1; ++e) {
            int2 pr = ov_pairs[e];                  // uniform -> SGPR
            int row = pr.x >> 16;
            int off = pr.x & 0xFFFF;
            float v = __int_as_float(pr.y);
            const float* q = (const float*)(xf + off);
            float d0 = v * q[0], d1 = v * q[1], d2 = v * q[2];
#pragma unroll
            for (int R = 0; R < RPW; ++R) {
                if (row == rowbase + R) {           // wave-uniform compare
                    y[R][0] += d0; y[R][1] += d1; y[R][2] += d2;
                }
            }
        }

        // --- phase 3: static finish: W, bias, ReLU, accumulate --------------
#pragma unroll
        for (int R = 0; R < RPW; ++R)
#pragma unroll
            for (int ch = 0; ch < CH; ++ch) {
                float t = y[R][0] * sW[0 * CH + ch]
                        + y[R][1] * sW[1 * CH + ch]
                        + y[R][2] * sW[2 * CH + ch]
                        + sb[ch];
                acc[R][ch] += fmaxf(t, 0.f);
            }
    }

    // per-wave butterfly reduce over 64 lanes (frames); lane 0 stores its rows
#pragma unroll
    for (int R = 0; R < RPW; ++R)
#pragma unroll
        for (int ch = 0; ch < CH; ++ch) {
            float v = acc[R][ch];
#pragma unroll
            for (int m = 1; m < 64; m <<= 1) v += __shfl_xor(v, m, 64);
            acc[R][ch] = v;
        }
    if (lane == 0) {
#pragma unroll
        for (int R = 0; R < RPW; ++R) {
            int j = rowbase + R;
            if (j < J) {
#pragma unroll
                for (int ch = 0; ch < CH; ++ch)
                    partials[(size_t)blockIdx.x * JC + j * CH + ch] = acc[R][ch];
            }
        }
    }
}

// ---- finalize: mean over frames + fc + sigmoid ------------------------------
__global__ void finalize_kernel(const float* __restrict__ partials,
                                const float* __restrict__ fcW,
                                const float* __restrict__ fcb,
                                float* __restrict__ out) {
    __shared__ float h[JC];
    int b = blockIdx.x, tid = threadIdx.x;
    if (tid < JC) {
        float a = 0.f;
#pragma unroll
        for (int p = 0; p < BPB; ++p)
            a += partials[(size_t)(b * BPB + p) * JC + tid];
        a *= (1.0f / (float)T);
        h[tid] = a;
        out[(size_t)b * JC + tid] = a;
    }
    __syncthreads();
    if (tid < 2) {
        float a = fcb[tid];
        for (int r = 0; r < JC; ++r) a += h[r] * fcW[r * 2 + tid];
        out[(size_t)B * JC + b * 2 + tid] = 1.0f / (1.0f + expf(-a));
    }
}

extern "C" void kernel_launch(void* const* d_in, const int* in_sizes, int n_in,
                              void* d_out, int out_size, void* d_ws, size_t ws_size,
                              hipStream_t stream) {
    const float* x   = (const float*)d_in[0];
    const int*   ei  = (const int*)d_in[1];
    const float* W   = (const float*)d_in[4];
    const float* bb  = (const float*)d_in[5];
    const float* fcW = (const float*)d_in[6];
    const float* fcb = (const float*)d_in[7];

    char* ws = (char*)d_ws;
    int2* pairs    = (int2*)ws;                       // 192 * 8B
    int2* ov_pairs = pairs + PROWS * SLOTS;           // 96 * 8B
    int*  ov_rp    = (int*)(ov_pairs + MAXOV);        // 33 * 4B
    float* partials = (float*)(ws + 4096);            // 1024*87 floats

    prep_kernel<<<1, 64, 0, stream>>>(ei, pairs, ov_rp, ov_pairs);
    gcn_main<<<NBLK, WAVES * 64, 0, stream>>>(x, W, bb, pairs, ov_rp, ov_pairs, partials);
    finalize_kernel<<<B, 128, 0, stream>>>(partials, fcW, fcb, (float*)d_out);
}

// Round 8
// 44.070 us; speedup vs baseline: 3.9272x; 1.0064x over previous
//
#include <hip/hip_runtime.h>
#include <math.h>

#define J   29
#define CH  3
#define JC  87            // J*CH
#define E0  56
#define B   256
#define T   1024
#define FRAMES (B*T)      // 262144
#define FPC 64            // frames per chunk (= lanes)
#define CPB 4             // chunks per block
#define NBLK (FRAMES/(FPC*CPB)) // 1024
#define CHUNK_FLOATS (FPC*JC)   // 5568 floats
#define CHUNK_BYTES (CHUNK_FLOATS*4) // 22272
#define BPB (T/(FPC*CPB)) // 4 partials per batch
#define SLOTS 4           // padded nnz per row (overflow beyond)
#define PROWS 32          // padded row count (rows 29..31 = zeros)
#define MAXOV 96          // overflow capacity
#define WAVES 8           // waves per main block
#define RPW 4             // rows per wave
#define NROUND 29         // staging rounds: 29 x 1KB = 29696 B padded chunk

typedef const __attribute__((address_space(1))) void* gas_p;
typedef __attribute__((address_space(3))) void* las_p;

// ---- prep: M = D^-1/2(A+I)D^-1/2 as padded-4 slots + row-tagged overflow ---
// slot pr.x = col*16 (byte offset in padded LDS layout); ov pr.x = row<<16|col*16
__global__ void prep_kernel(const int* __restrict__ ei,
                            int2* __restrict__ pairs,    // [PROWS*SLOTS]
                            int*  __restrict__ ov_rp,    // [33]
                            int2* __restrict__ ov_pairs) // [MAXOV]
{
    __shared__ float M[J * J];
    __shared__ float dinv[J];
    __shared__ int   cnt_ov[J];
    int tid = threadIdx.x;

    for (int i = tid; i < J * J; i += 64) M[i] = 0.f;
    if (tid < J) {
        int d = 1;
        for (int e = 0; e < E0; ++e) d += (ei[E0 + e] == tid) ? 1 : 0;
        dinv[tid] = rsqrtf((float)d);
    }
    __syncthreads();

    if (tid < J) {
        for (int e = 0; e < E0; ++e) {
            if (ei[E0 + e] == tid) {
                int s = ei[e];
                M[tid * J + s] += dinv[s] * dinv[tid];
            }
        }
        M[tid * J + tid] += dinv[tid] * dinv[tid];
        int c = 0;
        for (int i = 0; i < J; ++i) c += (M[tid * J + i] != 0.f) ? 1 : 0;
        cnt_ov[tid] = (c > SLOTS) ? (c - SLOTS) : 0;
    }
    __syncthreads();

    if (tid == 0) {
        int a = 0;
        for (int j = 0; j < J; ++j) { ov_rp[j] = a; a += cnt_ov[j]; }
        for (int j = J; j <= 32; ++j) ov_rp[j] = a;   // rows 29..31 empty
    }
    __syncthreads();

    if (tid < PROWS) {
        int2 zero; zero.x = 0; zero.y = 0;
        if (tid < J) {
            int s = 0, p = ov_rp[tid];
            for (int i = 0; i < J; ++i) {
                float v = M[tid * J + i];
                if (v != 0.f) {
                    if (s < SLOTS) {
                        int2 pr; pr.x = i * 16; pr.y = __float_as_int(v);
                        pairs[tid * SLOTS + s] = pr;
                    } else {
                        int2 pr; pr.x = (tid << 16) | (i * 16); pr.y = __float_as_int(v);
                        ov_pairs[p++] = pr;
                    }
                    ++s;
                }
            }
            for (; s < SLOTS; ++s) pairs[tid * SLOTS + s] = zero;
        } else {
            for (int s = 0; s < SLOTS; ++s) pairs[tid * SLOTS + s] = zero;
        }
    }
    __syncthreads();
    if (tid == 0) {
        int a = ov_rp[J];
        for (int i = a; i < MAXOV; ++i) { int2 pr; pr.x = 0; pr.y = 0; ov_pairs[i] = pr; }
    }
}

// ---- main: 8 waves/block, 4 rows/wave, padded-16B LDS, b128 gathers --------
__launch_bounds__(512, 6)
__global__ void gcn_main(const float* __restrict__ x,
                         const float* __restrict__ Wp,
                         const float* __restrict__ bp,
                         const int2* __restrict__ pairs,
                         const int*  __restrict__ ov_rp,
                         const int2* __restrict__ ov_pairs,
                         float* __restrict__ partials) {
    // padded chunk: [64 frames][29 joints][4 floats (3 data + 1 pad)] = 29696 B
    __shared__ float4 xs4[FPC * J];

    int tid  = threadIdx.x;
    int lane = tid & 63;
    int wv   = tid >> 6;
    int rowbase = __builtin_amdgcn_readfirstlane(wv * RPW);  // uniform 0,4,..,28

    // wave-uniform small tables -> scalar loads, hoisted out of the chunk loop
    float sW[9], sb[CH];
#pragma unroll
    for (int i = 0; i < 9; ++i) sW[i] = Wp[i];
#pragma unroll
    for (int i = 0; i < CH; ++i) sb[i] = bp[i];
    int ov0 = ov_rp[rowbase], ov1 = ov_rp[rowbase + RPW];

    const char* src = (const char*)(x + (size_t)blockIdx.x * (CPB * CHUNK_FLOATS));
    char* dst = (char*)xs4;
    const bool lastBlock = (blockIdx.x == NBLK - 1);

    float acc[RPW][CH];
#pragma unroll
    for (int r = 0; r < RPW; ++r)
#pragma unroll
        for (int c = 0; c < CH; ++c) acc[r][c] = 0.f;

    for (int c = 0; c < CPB; ++c) {
        __syncthreads();   // previous chunk fully consumed
        const char* s = src + (size_t)c * CHUNK_BYTES;
        const bool lastChunk = lastBlock && (c == CPB - 1);
        // pre-swizzled per-lane global source; linear LDS dest (base + lane*16).
        // round r, lane L: LDS slot r*64+L <- global bytes [768r+12L, +16)
        // (4B of junk lands in the pad dword of each slot — never read)
        for (int r = wv; r < NROUND; r += WAVES) {
            int goff = r * 768 + lane * 12;
            // very last 16B of the whole array would read 4B past x: clamp
            if (lastChunk && r == NROUND - 1)
                goff = (goff > CHUNK_BYTES - 16) ? (CHUNK_BYTES - 16) : goff;
            __builtin_amdgcn_global_load_lds((gas_p)(s + goff),
                                             (las_p)(dst + r * 1024), 16, 0, 0);
        }
        asm volatile("s_waitcnt vmcnt(0)" ::: "memory");
        // repair the clamped slot (this wave staged round 28, its loads are done)
        if (lastChunk && wv == (NROUND - 1) % WAVES && lane == 0) {
            volatile float* slot = (volatile float*)(xs4 + (FPC * J - 1));
            float a = slot[1], b2 = slot[2], c2 = slot[3];
            slot[0] = a; slot[1] = b2; slot[2] = c2;
        }
        __syncthreads();

        const char* xf = (const char*)xs4 + lane * (J * 16);

        // --- phase 1: static gather, one ds_read_b128 per slot --------------
        float y[RPW][CH];
#pragma unroll
        for (int R = 0; R < RPW; ++R) {
            float a0 = 0.f, a1 = 0.f, a2 = 0.f;
#pragma unroll
            for (int sl = 0; sl < SLOTS; ++sl) {
                int2 pr = pairs[(rowbase + R) * SLOTS + sl];  // SGPR (uniform)
                float v = __int_as_float(pr.y);
                float4 q = *(const float4*)(xf + pr.x);       // ds_read_b128
                a0 += v * q.x;
                a1 += v * q.y;
                a2 += v * q.z;
            }
            y[R][0] = a0; y[R][1] = a1; y[R][2] = a2;
        }

        // --- phase 2: overflow (uniform bounds, STATIC y indices) -----------
        for (int e = ov0; e < ov1; ++e) {
            int2 pr = ov_pairs[e];                 // uniform -> SGPR
            int row = pr.x >> 16;
            int off = pr.x & 0xFFFF;
            float v = __int_as_float(pr.y);
            float4 q = *(const float4*)(xf + off);
            float d0 = v * q.x, d1 = v * q.y, d2 = v * q.z;
#pragma unroll
            for (int R = 0; R < RPW; ++R) {
                if (row == rowbase + R) {          // wave-uniform compare
                    y[R][0] += d0; y[R][1] += d1; y[R][2] += d2;
                }
            }
        }

        // --- phase 3: static finish: W, bias, ReLU, accumulate --------------
#pragma unroll
        for (int R = 0; R < RPW; ++R)
#pragma unroll
            for (int ch = 0; ch < CH; ++ch) {
                float t = y[R][0] * sW[0 * CH + ch]
                        + y[R][1] * sW[1 * CH + ch]
                        + y[R][2] * sW[2 * CH + ch]
                        + sb[ch];
                acc[R][ch] += fmaxf(t, 0.f);
            }
    }

    // per-wave butterfly reduce over 64 lanes (frames); lane 0 stores its rows
#pragma unroll
    for (int R = 0; R < RPW; ++R)
#pragma unroll
        for (int ch = 0; ch < CH; ++ch) {
            float v = acc[R][ch];
#pragma unroll
            for (int m = 1; m < 64; m <<= 1) v += __shfl_xor(v, m, 64);
            acc[R][ch] = v;
        }
    if (lane == 0) {
#pragma unroll
        for (int R = 0; R < RPW; ++R) {
            int j = rowbase + R;
            if (j < J) {
#pragma unroll
                for (int ch = 0; ch < CH; ++ch)
                    partials[(size_t)blockIdx.x * JC + j * CH + ch] = acc[R][ch];
            }
        }
    }
}

// ---- finalize: mean over frames + fc + sigmoid ------------------------------
__global__ void finalize_kernel(const float* __restrict__ partials,
                                const float* __restrict__ fcW,
                                const float* __restrict__ fcb,
                                float* __restrict__ out) {
    __shared__ float h[JC];
    int b = blockIdx.x, tid = threadIdx.x;
    if (tid < JC) {
        float a = 0.f;
#pragma unroll
        for (int p = 0; p < BPB; ++p)
            a += partials[(size_t)(b * BPB + p) * JC + tid];
        a *= (1.0f / (float)T);
        h[tid] = a;
        out[(size_t)b * JC + tid] = a;
    }
    __syncthreads();
    if (tid < 2) {
        float a = fcb[tid];
        for (int r = 0; r < JC; ++r) a += h[r] * fcW[r * 2 + tid];
        out[(size_t)B * JC + b * 2 + tid] = 1.0f / (1.0f + expf(-a));
    }
}

extern "C" void kernel_launch(void* const* d_in, const int* in_sizes, int n_in,
                              void* d_out, int out_size, void* d_ws, size_t ws_size,
                              hipStream_t stream) {
    const float* x   = (const float*)d_in[0];
    const int*   ei  = (const int*)d_in[1];
    const float* W   = (const float*)d_in[4];
    const float* bb  = (const float*)d_in[5];
    const float* fcW = (const float*)d_in[6];
    const float* fcb = (const float*)d_in[7];

    char* ws = (char*)d_ws;
    int2* pairs    = (int2*)ws;                       // 128 * 8B
    int2* ov_pairs = pairs + PROWS * SLOTS;           // 96 * 8B
    int*  ov_rp    = (int*)(ov_pairs + MAXOV);        // 33 * 4B
    float* partials = (float*)(ws + 4096);            // 1024*87 floats

    prep_kernel<<<1, 64, 0, stream>>>(ei, pairs, ov_rp, ov_pairs);
    gcn_main<<<NBLK, WAVES * 64, 0, stream>>>(x, W, bb, pairs, ov_rp, ov_pairs, partials);
    finalize_kernel<<<B, 128, 0, stream>>>(partials, fcW, fcb, (float*)d_out);
}

// Round 9
// 42.548 us; speedup vs baseline: 4.0677x; 1.0358x over previous
//
#include <hip/hip_runtime.h>
#include <math.h>

#define J   29
#define CH  3
#define JC  87            // J*CH
#define E0  56
#define B   256
#define T   1024
#define FRAMES (B*T)      // 262144
#define FPC 64            // frames per chunk (= lanes)
#define CPB 8             // chunks per block
#define NBLK (FRAMES/(FPC*CPB)) // 512 -> exactly 2 blocks/CU, one generation
#define CHUNK_FLOATS (FPC*JC)   // 5568 floats
#define CHUNK_BYTES (CHUNK_FLOATS*4) // 22272
#define BPB (T/(FPC*CPB)) // 2 partials per batch
#define SLOTS 4           // padded nnz per row (overflow beyond)
#define PROWS 32          // padded row count (rows 29..31 = zeros)
#define MAXOV 96          // overflow capacity
#define WAVES 8           // waves per main block
#define RPW 4             // rows per wave
#define NROUND 29         // staging rounds: 29 x 1KB = 29696 B padded chunk

typedef const __attribute__((address_space(1))) void* gas_p;
typedef __attribute__((address_space(3))) void* las_p;

// ---- prep: M = D^-1/2(A+I)D^-1/2 as padded-4 slots + row-tagged overflow ---
// slot pr.x = col*16 (byte offset in padded LDS layout); ov pr.x = row<<16|col*16
__global__ void prep_kernel(const int* __restrict__ ei,
                            int2* __restrict__ pairs,    // [PROWS*SLOTS]
                            int*  __restrict__ ov_rp,    // [33]
                            int2* __restrict__ ov_pairs) // [MAXOV]
{
    __shared__ float M[J * J];
    __shared__ float dinv[J];
    __shared__ int   cnt_ov[J];
    int tid = threadIdx.x;

    for (int i = tid; i < J * J; i += 64) M[i] = 0.f;
    if (tid < J) {
        int d = 1;
        for (int e = 0; e < E0; ++e) d += (ei[E0 + e] == tid) ? 1 : 0;
        dinv[tid] = rsqrtf((float)d);
    }
    __syncthreads();

    if (tid < J) {
        for (int e = 0; e < E0; ++e) {
            if (ei[E0 + e] == tid) {
                int s = ei[e];
                M[tid * J + s] += dinv[s] * dinv[tid];
            }
        }
        M[tid * J + tid] += dinv[tid] * dinv[tid];
        int c = 0;
        for (int i = 0; i < J; ++i) c += (M[tid * J + i] != 0.f) ? 1 : 0;
        cnt_ov[tid] = (c > SLOTS) ? (c - SLOTS) : 0;
    }
    __syncthreads();

    if (tid == 0) {
        int a = 0;
        for (int j = 0; j < J; ++j) { ov_rp[j] = a; a += cnt_ov[j]; }
        for (int j = J; j <= 32; ++j) ov_rp[j] = a;   // rows 29..31 empty
    }
    __syncthreads();

    if (tid < PROWS) {
        int2 zero; zero.x = 0; zero.y = 0;
        if (tid < J) {
            int s = 0, p = ov_rp[tid];
            for (int i = 0; i < J; ++i) {
                float v = M[tid * J + i];
                if (v != 0.f) {
                    if (s < SLOTS) {
                        int2 pr; pr.x = i * 16; pr.y = __float_as_int(v);
                        pairs[tid * SLOTS + s] = pr;
                    } else {
                        int2 pr; pr.x = (tid << 16) | (i * 16); pr.y = __float_as_int(v);
                        ov_pairs[p++] = pr;
                    }
                    ++s;
                }
            }
            for (; s < SLOTS; ++s) pairs[tid * SLOTS + s] = zero;
        } else {
            for (int s = 0; s < SLOTS; ++s) pairs[tid * SLOTS + s] = zero;
        }
    }
    __syncthreads();
    if (tid == 0) {
        int a = ov_rp[J];
        for (int i = a; i < MAXOV; ++i) { int2 pr; pr.x = 0; pr.y = 0; ov_pairs[i] = pr; }
    }
}

// stage one padded chunk: round r (1KB) staged by wave r%8; lane L's global
// src = 768r + 12L (pre-swizzle), LDS dst linear = r*1024 + L*16.
__device__ __forceinline__ void stage_chunk(const char* __restrict__ s,
                                            char* d, int lane, int wv,
                                            bool lastChunk) {
    for (int r = wv; r < NROUND; r += WAVES) {
        int goff = r * 768 + lane * 12;
        if (lastChunk && r == NROUND - 1)
            goff = (goff > CHUNK_BYTES - 16) ? (CHUNK_BYTES - 16) : goff;
        __builtin_amdgcn_global_load_lds((gas_p)(s + goff),
                                         (las_p)(d + r * 1024), 16, 0, 0);
    }
}

// ---- main: 8 waves/block, double-buffered, counted-vmcnt pipeline ----------
__launch_bounds__(512, 4)
__global__ void gcn_main(const float* __restrict__ x,
                         const float* __restrict__ Wp,
                         const float* __restrict__ bp,
                         const int2* __restrict__ pairs,
                         const int*  __restrict__ ov_rp,
                         const int2* __restrict__ ov_pairs,
                         float* __restrict__ partials) {
    __shared__ float4 xs4[2][FPC * J];   // 2 x 29696 B
    __shared__ int2   s_ovp[MAXOV];      // overflow table (ds_read, not vmcnt)

    int tid  = threadIdx.x;
    int lane = tid & 63;
    int wv   = tid >> 6;
    int rowbase = __builtin_amdgcn_readfirstlane(wv * RPW);  // uniform 0,4,..,28

    // ---- hoist ALL global table reads before any staging (vmcnt hygiene) ---
    float sW[9], sb[CH];
#pragma unroll
    for (int i = 0; i < 9; ++i) sW[i] = Wp[i];
#pragma unroll
    for (int i = 0; i < CH; ++i) sb[i] = bp[i];
    int ov0 = ov_rp[rowbase], ov1 = ov_rp[rowbase + RPW];
    int2 pr_[RPW][SLOTS];
#pragma unroll
    for (int R = 0; R < RPW; ++R)
#pragma unroll
        for (int sl = 0; sl < SLOTS; ++sl)
            pr_[R][sl] = pairs[(rowbase + R) * SLOTS + sl];
    if (tid < MAXOV) s_ovp[tid] = ov_pairs[tid];
    __syncthreads();   // drains everything; nothing to preserve yet

    const char* src = (const char*)(x + (size_t)blockIdx.x * (CPB * CHUNK_FLOATS));
    const bool lastBlock = (blockIdx.x == NBLK - 1);

    float acc[RPW][CH];
#pragma unroll
    for (int r = 0; r < RPW; ++r)
#pragma unroll
        for (int c = 0; c < CH; ++c) acc[r][c] = 0.f;

    // prologue: stage chunk 0 -> buf 0 (in flight across barrier #1 of iter 0)
    stage_chunk(src, (char*)xs4[0], lane, wv, false);

    for (int c = 0; c < CPB; ++c) {
        float4* bufc = xs4[c & 1];
        const bool lastChunk = lastBlock && (c == CPB - 1);

        // barrier #1: all waves done reading buf[(c+1)&1] (chunk c-1)
        asm volatile("" ::: "memory");
        __builtin_amdgcn_s_barrier();
        asm volatile("" ::: "memory");

        if (c + 1 < CPB) {
            // issue next chunk into the freed buffer; it flies across compute
            stage_chunk(src + (size_t)(c + 1) * CHUNK_BYTES,
                        (char*)xs4[(c + 1) & 1], lane, wv,
                        lastBlock && (c + 1 == CPB - 1));
            // wait only for chunk c's own loads (oldest); keep c+1 in flight
            if (wv < 5) asm volatile("s_waitcnt vmcnt(4)" ::: "memory");
            else        asm volatile("s_waitcnt vmcnt(3)" ::: "memory");
        } else {
            asm volatile("s_waitcnt vmcnt(0)" ::: "memory");
        }

        // repair the clamped tail slot (only last chunk of last block)
        if (lastChunk && wv == 4 && lane == 0) {
            volatile float* slot = (volatile float*)(bufc + (FPC * J - 1));
            float a = slot[1], b2 = slot[2], c2 = slot[3];
            slot[0] = a; slot[1] = b2; slot[2] = c2;
            asm volatile("s_waitcnt lgkmcnt(0)" ::: "memory");
        }

        // barrier #2: all waves' chunk-c loads landed
        asm volatile("" ::: "memory");
        __builtin_amdgcn_s_barrier();
        __builtin_amdgcn_sched_barrier(0);

        const char* xf = (const char*)bufc + lane * (J * 16);

        // phase 1: static gather, one ds_read_b128 per slot
        float y[RPW][CH];
#pragma unroll
        for (int R = 0; R < RPW; ++R) {
            float a0 = 0.f, a1 = 0.f, a2 = 0.f;
#pragma unroll
            for (int sl = 0; sl < SLOTS; ++sl) {
                int2 pr = pr_[R][sl];
                float v = __int_as_float(pr.y);
                float4 q = *(const float4*)(xf + pr.x);
                a0 += v * q.x;
                a1 += v * q.y;
                a2 += v * q.z;
            }
            y[R][0] = a0; y[R][1] = a1; y[R][2] = a2;
        }

        // phase 2: overflow via LDS table (uniform bounds, static y indices)
        for (int e = ov0; e < ov1; ++e) {
            int2 pr = s_ovp[e];
            int row = pr.x >> 16;
            int off = pr.x & 0xFFFF;
            float v = __int_as_float(pr.y);
            float4 q = *(const float4*)(xf + off);
            float d0 = v * q.x, d1 = v * q.y, d2 = v * q.z;
#pragma unroll
            for (int R = 0; R < RPW; ++R) {
                if (row == rowbase + R) {
                    y[R][0] += d0; y[R][1] += d1; y[R][2] += d2;
                }
            }
        }

        // phase 3: W, bias, ReLU, accumulate
#pragma unroll
        for (int R = 0; R < RPW; ++R)
#pragma unroll
            for (int ch = 0; ch < CH; ++ch) {
                float t = y[R][0] * sW[0 * CH + ch]
                        + y[R][1] * sW[1 * CH + ch]
                        + y[R][2] * sW[2 * CH + ch]
                        + sb[ch];
                acc[R][ch] += fmaxf(t, 0.f);
            }
    }

    // per-wave butterfly reduce over 64 lanes (frames); lane 0 stores its rows
#pragma unroll
    for (int R = 0; R < RPW; ++R)
#pragma unroll
        for (int ch = 0; ch < CH; ++ch) {
            float v = acc[R][ch];
#pragma unroll
            for (int m = 1; m < 64; m <<= 1) v += __shfl_xor(v, m, 64);
            acc[R][ch] = v;
        }
    if (lane == 0) {
#pragma unroll
        for (int R = 0; R < RPW; ++R) {
            int j = rowbase + R;
            if (j < J) {
#pragma unroll
                for (int ch = 0; ch < CH; ++ch)
                    partials[(size_t)blockIdx.x * JC + j * CH + ch] = acc[R][ch];
            }
        }
    }
}

// ---- finalize: mean over frames + fc + sigmoid ------------------------------
__global__ void finalize_kernel(const float* __restrict__ partials,
                                const float* __restrict__ fcW,
                                const float* __restrict__ fcb,
                                float* __restrict__ out) {
    __shared__ float h[JC];
    int b = blockIdx.x, tid = threadIdx.x;
    if (tid < JC) {
        float a = 0.f;
#pragma unroll
        for (int p = 0; p < BPB; ++p)
            a += partials[(size_t)(b * BPB + p) * JC + tid];
        a *= (1.0f / (float)T);
        h[tid] = a;
        out[(size_t)b * JC + tid] = a;
    }
    __syncthreads();
    if (tid < 2) {
        float a = fcb[tid];
        for (int r = 0; r < JC; ++r) a += h[r] * fcW[r * 2 + tid];
        out[(size_t)B * JC + b * 2 + tid] = 1.0f / (1.0f + expf(-a));
    }
}

extern "C" void kernel_launch(void* const* d_in, const int* in_sizes, int n_in,
                              void* d_out, int out_size, void* d_ws, size_t ws_size,
                              hipStream_t stream) {
    const float* x   = (const float*)d_in[0];
    const int*   ei  = (const int*)d_in[1];
    const float* W   = (const float*)d_in[4];
    const float* bb  = (const float*)d_in[5];
    const float* fcW = (const float*)d_in[6];
    const float* fcb = (const float*)d_in[7];

    char* ws = (char*)d_ws;
    int2* pairs    = (int2*)ws;                       // 128 * 8B
    int2* ov_pairs = pairs + PROWS * SLOTS;           // 96 * 8B
    int*  ov_rp    = (int*)(ov_pairs + MAXOV);        // 33 * 4B
    float* partials = (float*)(ws + 4096);            // 512*87 floats

    prep_kernel<<<1, 64, 0, stream>>>(ei, pairs, ov_rp, ov_pairs);
    gcn_main<<<NBLK, WAVES * 64, 0, stream>>>(x, W, bb, pairs, ov_rp, ov_pairs, partials);
    finalize_kernel<<<B, 128, 0, stream>>>(partials, fcW, fcb, (float*)d_out);
}